// Round 1
// 1451.957 us; speedup vs baseline: 1.1701x; 1.1701x over previous
//
#include <hip/hip_runtime.h>
#include <hip/hip_bf16.h>

#define E_ 16
#define H_ 2048
#define I_ 1408
#define BM 128
#define BN 128
#define BK 32
#define SB 48   // LDS row stride in bf16 elems (96 B, 16B-aligned rows)

typedef __attribute__((ext_vector_type(8))) short bf16x8;
typedef __attribute__((ext_vector_type(4))) float f32x4;

// Swizzled LDS offset: row-major [row][k], stride SB, with the four 16B
// k-chunks rotated by (row>>2)&3 to break the 96B-row bank pattern.
__device__ __forceinline__ int swz(int row, int e) {
  return row * SB + ((((e >> 3) + (row >> 2)) & 3) << 3) + (e & 7);
}

__device__ __forceinline__ unsigned int pk2(float a, float b) {
  __hip_bfloat162 h = __float22bfloat162_rn(make_float2(a, b));
  unsigned int u;
  __builtin_memcpy(&u, &h, 4);
  return u;  // low 16 = a, high 16 = b
}

__device__ __forceinline__ unsigned short bf16b(float a) {
  unsigned int u = __builtin_bit_cast(unsigned int, a);
  u = (u + 0x7fffu + ((u >> 16) & 1u)) >> 16;  // RNE
  return (unsigned short)u;
}

// ---------------- Router: logits (fp64) -> top-2 -> renorm weights ----------
__global__ __launch_bounds__(64) void moe_router(
    const float* __restrict__ x, const float* __restrict__ gw,
    int* __restrict__ counts, int* __restrict__ list2s,
    float* __restrict__ listw, int T)
{
  const int lane = threadIdx.x;
  const int t0 = blockIdx.x * 4;
  double acc[4][16];
#pragma unroll
  for (int i = 0; i < 4; ++i)
#pragma unroll
    for (int j = 0; j < 16; ++j) acc[i][j] = 0.0;

  const float4* gw4 = (const float4*)gw;
  for (int it = 0; it < H_ / 64; ++it) {
    const int h = it * 64 + lane;
    float gv[16];
    *(float4*)&gv[0]  = gw4[h * 4 + 0];
    *(float4*)&gv[4]  = gw4[h * 4 + 1];
    *(float4*)&gv[8]  = gw4[h * 4 + 2];
    *(float4*)&gv[12] = gw4[h * 4 + 3];
    float xr[4];
#pragma unroll
    for (int i = 0; i < 4; ++i) xr[i] = x[(size_t)(t0 + i) * H_ + h];
#pragma unroll
    for (int i = 0; i < 4; ++i) {
      const double xv = (double)xr[i];
#pragma unroll
      for (int j = 0; j < 16; ++j) acc[i][j] += xv * (double)gv[j];
    }
  }
#pragma unroll
  for (int i = 0; i < 4; ++i)
#pragma unroll
    for (int j = 0; j < 16; ++j) {
      double v = acc[i][j];
#pragma unroll
      for (int m = 32; m > 0; m >>= 1) v += __shfl_xor(v, m, 64);
      acc[i][j] = v;
    }
  if (lane == 0) {
#pragma unroll
    for (int i = 0; i < 4; ++i) {
      const int t = t0 + i;
      double b1 = -1e300, b2 = -1e300;
      int i1 = 0, i2 = 0;
#pragma unroll
      for (int j = 0; j < 16; ++j) {
        const double l = acc[i][j];
        if (l > b1) { b2 = b1; i2 = i1; b1 = l; i1 = j; }
        else if (l > b2) { b2 = l; i2 = j; }
      }
      const float ex = expf((float)(b2 - b1));
      const float wa = 1.f / (1.f + ex);
      const float wb = ex / (1.f + ex);
      int p = atomicAdd(&counts[i1], 1);
      list2s[i1 * T + p] = t * 2;
      listw[i1 * T + p] = wa;
      p = atomicAdd(&counts[i2], 1);
      list2s[i2 * T + p] = t * 2 + 1;
      listw[i2 * T + p] = wb;
    }
  }
}

// ---------------- Weight/activation pre-conversion to bf16 ------------------
// x [T][H] fp32 -> xb [T][H] bf16 (straight convert, 8 elems/thread)
__global__ __launch_bounds__(256) void convert_x(
    const float* __restrict__ x, unsigned short* __restrict__ xb)
{
  const size_t idx = ((size_t)blockIdx.x * 256 + threadIdx.x) * 8;
  const float4 f0 = *(const float4*)(x + idx);
  const float4 f1 = *(const float4*)(x + idx + 4);
  uint4 o;
  o.x = pk2(f0.x, f0.y); o.y = pk2(f0.z, f0.w);
  o.z = pk2(f1.x, f1.y); o.w = pk2(f1.z, f1.w);
  *(uint4*)(xb + idx) = o;
}

// src [E][R][C] fp32 -> dst [E][C][R] bf16 (transpose-convert).
// Thread handles an 8(r) x 8(c) patch; 128x128 tile per 256-thread block.
// Reads: 16 lanes x 32B contiguous per r-row; writes: same-tn lanes cover
// 64B-contiguous sectors per c-row (no write amplification).
__global__ __launch_bounds__(256) void convert_wT(
    const float* __restrict__ src, unsigned short* __restrict__ dst,
    int R, int C)
{
  const int e = blockIdx.z;
  src += (size_t)e * R * C;
  dst += (size_t)e * C * R;
  const int r0 = blockIdx.y * 128 + (threadIdx.x >> 4) * 8;
  const int c0 = blockIdx.x * 128 + (threadIdx.x & 15) * 8;
  float av[8][8];
#pragma unroll
  for (int j = 0; j < 8; ++j) {
    const float4 t0 = *(const float4*)(src + (size_t)(r0 + j) * C + c0);
    const float4 t1 = *(const float4*)(src + (size_t)(r0 + j) * C + c0 + 4);
    av[j][0] = t0.x; av[j][1] = t0.y; av[j][2] = t0.z; av[j][3] = t0.w;
    av[j][4] = t1.x; av[j][5] = t1.y; av[j][6] = t1.z; av[j][7] = t1.w;
  }
#pragma unroll
  for (int n = 0; n < 8; ++n) {
    uint4 o;
    o.x = pk2(av[0][n], av[1][n]);
    o.y = pk2(av[2][n], av[3][n]);
    o.z = pk2(av[4][n], av[5][n]);
    o.w = pk2(av[6][n], av[7][n]);
    *(uint4*)(dst + (size_t)(c0 + n) * R + r0) = o;
  }
}

// ---------------- GEMM1 (bf16 weights, [I][H] layout) -----------------------
__global__ __launch_bounds__(256) void moe_gemm1_b16(
    const unsigned short* __restrict__ xb, const unsigned short* __restrict__ w1b,
    const unsigned short* __restrict__ w3b, const int* __restrict__ counts,
    const int* __restrict__ list2s, unsigned short* __restrict__ act, int T)
{
  const int e = blockIdx.z;
  const int cnt = counts[e];
  const int m0 = blockIdx.y * BM;
  if (m0 >= cnt) return;
  const int n0 = blockIdx.x * BN;
  const unsigned short* w1e = w1b + (size_t)e * H_ * I_;  // [I_][H_]
  const unsigned short* w3e = w3b + (size_t)e * H_ * I_;
  const int* lst = list2s + (size_t)e * T;

  __shared__ unsigned short As[BM * SB], B1s[BN * SB], B3s[BN * SB];

  const int tid = threadIdx.x;
  const int lane = tid & 63, wave = tid >> 6;
  const int wr = (wave >> 1) * 64, wc = (wave & 1) * 64;
  const int l16 = lane & 15, quad = lane >> 4;

  // staging: 2 threads per row (A and B share the same mapping)
  const int ar = tid >> 1, ahalf = tid & 1;
  const int apos = m0 + ar;
  const int a_t2s = lst[apos < cnt ? apos : cnt - 1];
  const unsigned short* aptr = xb + (size_t)(a_t2s >> 1) * H_ + ahalf * 16;
  const unsigned short* b1p = w1e + (size_t)(n0 + ar) * H_ + ahalf * 16;
  const unsigned short* b3p = w3e + (size_t)(n0 + ar) * H_ + ahalf * 16;

  f32x4 acc1[4][4], acc3[4][4];
  const f32x4 fz = {0.f, 0.f, 0.f, 0.f};
#pragma unroll
  for (int mi = 0; mi < 4; ++mi)
#pragma unroll
    for (int ni = 0; ni < 4; ++ni) { acc1[mi][ni] = fz; acc3[mi][ni] = fz; }

  // register double-buffer: loads for tile k+1 issued before compute of tile k
  uint4 pA0, pA1, pB10, pB11, pB30, pB31;
  pA0  = *(const uint4*)(aptr);     pA1  = *(const uint4*)(aptr + 8);
  pB10 = *(const uint4*)(b1p);      pB11 = *(const uint4*)(b1p + 8);
  pB30 = *(const uint4*)(b3p);      pB31 = *(const uint4*)(b3p + 8);

  for (int k0 = 0; k0 < H_; k0 += BK) {
    __syncthreads();
    *(uint4*)&As[swz(ar, ahalf * 16)]      = pA0;
    *(uint4*)&As[swz(ar, ahalf * 16 + 8)]  = pA1;
    *(uint4*)&B1s[swz(ar, ahalf * 16)]     = pB10;
    *(uint4*)&B1s[swz(ar, ahalf * 16 + 8)] = pB11;
    *(uint4*)&B3s[swz(ar, ahalf * 16)]     = pB30;
    *(uint4*)&B3s[swz(ar, ahalf * 16 + 8)] = pB31;
    const int kn = (k0 + BK < H_) ? k0 + BK : 0;  // wrap: harmless re-read
    pA0  = *(const uint4*)(aptr + kn);     pA1  = *(const uint4*)(aptr + kn + 8);
    pB10 = *(const uint4*)(b1p + kn);      pB11 = *(const uint4*)(b1p + kn + 8);
    pB30 = *(const uint4*)(b3p + kn);      pB31 = *(const uint4*)(b3p + kn + 8);
    __syncthreads();

    bf16x8 af[4], b1f[4], b3f[4];
#pragma unroll
    for (int mi = 0; mi < 4; ++mi)
      af[mi] = *(const bf16x8*)&As[swz(wr + mi * 16 + l16, quad * 8)];
#pragma unroll
    for (int ni = 0; ni < 4; ++ni) {
      b1f[ni] = *(const bf16x8*)&B1s[swz(wc + ni * 16 + l16, quad * 8)];
      b3f[ni] = *(const bf16x8*)&B3s[swz(wc + ni * 16 + l16, quad * 8)];
    }
#pragma unroll
    for (int mi = 0; mi < 4; ++mi)
#pragma unroll
      for (int ni = 0; ni < 4; ++ni) {
        acc1[mi][ni] = __builtin_amdgcn_mfma_f32_16x16x32_bf16(af[mi], b1f[ni], acc1[mi][ni], 0, 0, 0);
        acc3[mi][ni] = __builtin_amdgcn_mfma_f32_16x16x32_bf16(af[mi], b3f[ni], acc3[mi][ni], 0, 0, 0);
      }
  }

#pragma unroll
  for (int mi = 0; mi < 4; ++mi) {
    const int rbase = m0 + wr + mi * 16 + quad * 4;
#pragma unroll
    for (int r = 0; r < 4; ++r) {
      const int pos = rbase + r;
      if (pos < cnt) {
        const int t2s = lst[pos];
        unsigned short* op = act + (size_t)t2s * I_ + n0 + wc + l16;
#pragma unroll
        for (int ni = 0; ni < 4; ++ni) {
          const float g = acc1[mi][ni][r];
          const float u = acc3[mi][ni][r];
          const float s = g / (1.f + __expf(-g));
          op[ni * 16] = bf16b(s * u);
        }
      }
    }
  }
}

// ---------------- GEMM2 (bf16 weights, [H][I] layout) -----------------------
__global__ __launch_bounds__(256) void moe_gemm2_b16(
    const unsigned short* __restrict__ act, const unsigned short* __restrict__ w2b,
    const int* __restrict__ counts, const int* __restrict__ list2s,
    const float* __restrict__ listw, float* __restrict__ out, int T)
{
  const int e = blockIdx.z;
  const int cnt = counts[e];
  const int m0 = blockIdx.y * BM;
  if (m0 >= cnt) return;
  const int n0 = blockIdx.x * BN;
  const unsigned short* w2e = w2b + (size_t)e * I_ * H_;  // [H_][I_]
  const int* lst = list2s + (size_t)e * T;
  const float* lw = listw + (size_t)e * T;

  __shared__ unsigned short As[BM * SB], Bs[BN * SB];

  const int tid = threadIdx.x;
  const int lane = tid & 63, wave = tid >> 6;
  const int wr = (wave >> 1) * 64, wc = (wave & 1) * 64;
  const int l16 = lane & 15, quad = lane >> 4;

  const int ar = tid >> 1, ahalf = tid & 1;
  const int apos = m0 + ar;
  const int a_t2s = lst[apos < cnt ? apos : cnt - 1];
  const unsigned short* aptr = act + (size_t)a_t2s * I_ + ahalf * 16;
  const unsigned short* bp = w2e + (size_t)(n0 + ar) * I_ + ahalf * 16;

  f32x4 acc[4][4];
  const f32x4 fz = {0.f, 0.f, 0.f, 0.f};
#pragma unroll
  for (int mi = 0; mi < 4; ++mi)
#pragma unroll
    for (int ni = 0; ni < 4; ++ni) acc[mi][ni] = fz;

  uint4 pA0, pA1, pB0, pB1;
  pA0 = *(const uint4*)(aptr);  pA1 = *(const uint4*)(aptr + 8);
  pB0 = *(const uint4*)(bp);    pB1 = *(const uint4*)(bp + 8);

  for (int k0 = 0; k0 < I_; k0 += BK) {
    __syncthreads();
    *(uint4*)&As[swz(ar, ahalf * 16)]     = pA0;
    *(uint4*)&As[swz(ar, ahalf * 16 + 8)] = pA1;
    *(uint4*)&Bs[swz(ar, ahalf * 16)]     = pB0;
    *(uint4*)&Bs[swz(ar, ahalf * 16 + 8)] = pB1;
    const int kn = (k0 + BK < I_) ? k0 + BK : 0;
    pA0 = *(const uint4*)(aptr + kn);  pA1 = *(const uint4*)(aptr + kn + 8);
    pB0 = *(const uint4*)(bp + kn);    pB1 = *(const uint4*)(bp + kn + 8);
    __syncthreads();

    bf16x8 af[4], bf[4];
#pragma unroll
    for (int mi = 0; mi < 4; ++mi)
      af[mi] = *(const bf16x8*)&As[swz(wr + mi * 16 + l16, quad * 8)];
#pragma unroll
    for (int ni = 0; ni < 4; ++ni)
      bf[ni] = *(const bf16x8*)&Bs[swz(wc + ni * 16 + l16, quad * 8)];
#pragma unroll
    for (int mi = 0; mi < 4; ++mi)
#pragma unroll
      for (int ni = 0; ni < 4; ++ni)
        acc[mi][ni] = __builtin_amdgcn_mfma_f32_16x16x32_bf16(af[mi], bf[ni], acc[mi][ni], 0, 0, 0);
  }

#pragma unroll
  for (int mi = 0; mi < 4; ++mi) {
    const int rbase = m0 + wr + mi * 16 + quad * 4;
#pragma unroll
    for (int r = 0; r < 4; ++r) {
      const int pos = rbase + r;
      if (pos < cnt) {
        const int t2s = lst[pos];
        const float wt = lw[pos];
        float* op = out + (size_t)(t2s >> 1) * H_ + n0 + wc + l16;
#pragma unroll
        for (int ni = 0; ni < 4; ++ni)
          atomicAdd(op + ni * 16, wt * acc[mi][ni][r]);
      }
    }
  }
}

// ---------------- Fallback fp32-weight kernels (verified path) --------------
__device__ __forceinline__ void stage_b(const float* __restrict__ bp,
                                        unsigned short* Bs, int bn, int bk, int ldb) {
  const float4 r0 = *(const float4*)(bp);
  const float4 r1 = *(const float4*)(bp + ldb);
  const float4 r2 = *(const float4*)(bp + 2 * ldb);
  const float4 r3 = *(const float4*)(bp + 3 * ldb);
  uint2 c;
  c.x = pk2(r0.x, r1.x); c.y = pk2(r2.x, r3.x);
  *(uint2*)&Bs[swz(bn + 0, bk)] = c;
  c.x = pk2(r0.y, r1.y); c.y = pk2(r2.y, r3.y);
  *(uint2*)&Bs[swz(bn + 1, bk)] = c;
  c.x = pk2(r0.z, r1.z); c.y = pk2(r2.z, r3.z);
  *(uint2*)&Bs[swz(bn + 2, bk)] = c;
  c.x = pk2(r0.w, r1.w); c.y = pk2(r2.w, r3.w);
  *(uint2*)&Bs[swz(bn + 3, bk)] = c;
}

__global__ __launch_bounds__(256) void moe_gemm1_f32(
    const float* __restrict__ x, const float* __restrict__ w1,
    const float* __restrict__ w3, const int* __restrict__ counts,
    const int* __restrict__ list2s, unsigned short* __restrict__ act, int T)
{
  const int e = blockIdx.z;
  const int cnt = counts[e];
  const int m0 = blockIdx.y * BM;
  if (m0 >= cnt) return;
  const int n0 = blockIdx.x * BN;
  const float* w1e = w1 + (size_t)e * H_ * I_;
  const float* w3e = w3 + (size_t)e * H_ * I_;
  const int* lst = list2s + (size_t)e * T;

  __shared__ unsigned short As[BM * SB], B1s[BN * SB], B3s[BN * SB];

  const int tid = threadIdx.x;
  const int lane = tid & 63, wave = tid >> 6;
  const int wr = (wave >> 1) * 64, wc = (wave & 1) * 64;
  const int l16 = lane & 15, quad = lane >> 4;

  const int ar = tid >> 1, ahalf = tid & 1;
  const int apos = m0 + ar;
  const int a_t2s = lst[apos < cnt ? apos : cnt - 1];
  const float* aptr = x + (size_t)(a_t2s >> 1) * H_ + ahalf * 16;

  const int nq = tid & 31, kb = tid >> 5;
  const int bn = nq * 4, bk = kb * 4;

  f32x4 acc1[4][4], acc3[4][4];
  const f32x4 fz = {0.f, 0.f, 0.f, 0.f};
#pragma unroll
  for (int mi = 0; mi < 4; ++mi)
#pragma unroll
    for (int ni = 0; ni < 4; ++ni) { acc1[mi][ni] = fz; acc3[mi][ni] = fz; }

  for (int k0 = 0; k0 < H_; k0 += BK) {
    __syncthreads();
    {
      const float4 a0 = *(const float4*)(aptr + k0);
      const float4 a1 = *(const float4*)(aptr + k0 + 4);
      const float4 a2 = *(const float4*)(aptr + k0 + 8);
      const float4 a3 = *(const float4*)(aptr + k0 + 12);
      uint4 A0, A1;
      A0.x = pk2(a0.x, a0.y); A0.y = pk2(a0.z, a0.w);
      A0.z = pk2(a1.x, a1.y); A0.w = pk2(a1.z, a1.w);
      A1.x = pk2(a2.x, a2.y); A1.y = pk2(a2.z, a2.w);
      A1.z = pk2(a3.x, a3.y); A1.w = pk2(a3.z, a3.w);
      *(uint4*)&As[swz(ar, ahalf * 16)] = A0;
      *(uint4*)&As[swz(ar, ahalf * 16 + 8)] = A1;
    }
    stage_b(w1e + (size_t)(k0 + bk) * I_ + n0 + bn, B1s, bn, bk, I_);
    stage_b(w3e + (size_t)(k0 + bk) * I_ + n0 + bn, B3s, bn, bk, I_);
    __syncthreads();

    bf16x8 af[4], b1f[4], b3f[4];
#pragma unroll
    for (int mi = 0; mi < 4; ++mi)
      af[mi] = *(const bf16x8*)&As[swz(wr + mi * 16 + l16, quad * 8)];
#pragma unroll
    for (int ni = 0; ni < 4; ++ni) {
      b1f[ni] = *(const bf16x8*)&B1s[swz(wc + ni * 16 + l16, quad * 8)];
      b3f[ni] = *(const bf16x8*)&B3s[swz(wc + ni * 16 + l16, quad * 8)];
    }
#pragma unroll
    for (int mi = 0; mi < 4; ++mi)
#pragma unroll
      for (int ni = 0; ni < 4; ++ni) {
        acc1[mi][ni] = __builtin_amdgcn_mfma_f32_16x16x32_bf16(af[mi], b1f[ni], acc1[mi][ni], 0, 0, 0);
        acc3[mi][ni] = __builtin_amdgcn_mfma_f32_16x16x32_bf16(af[mi], b3f[ni], acc3[mi][ni], 0, 0, 0);
      }
  }

#pragma unroll
  for (int mi = 0; mi < 4; ++mi) {
    const int rbase = m0 + wr + mi * 16 + quad * 4;
#pragma unroll
    for (int r = 0; r < 4; ++r) {
      const int pos = rbase + r;
      if (pos < cnt) {
        const int t2s = lst[pos];
        unsigned short* op = act + (size_t)t2s * I_ + n0 + wc + l16;
#pragma unroll
        for (int ni = 0; ni < 4; ++ni) {
          const float g = acc1[mi][ni][r];
          const float u = acc3[mi][ni][r];
          const float s = g / (1.f + __expf(-g));
          op[ni * 16] = bf16b(s * u);
        }
      }
    }
  }
}

__global__ __launch_bounds__(256) void moe_gemm2_f32(
    const unsigned short* __restrict__ act, const float* __restrict__ w2,
    const int* __restrict__ counts, const int* __restrict__ list2s,
    const float* __restrict__ listw, float* __restrict__ out, int T)
{
  const int e = blockIdx.z;
  const int cnt = counts[e];
  const int m0 = blockIdx.y * BM;
  if (m0 >= cnt) return;
  const int n0 = blockIdx.x * BN;
  const float* w2e = w2 + (size_t)e * I_ * H_;
  const int* lst = list2s + (size_t)e * T;
  const float* lw = listw + (size_t)e * T;

  __shared__ unsigned short As[BM * SB], Bs[BN * SB];

  const int tid = threadIdx.x;
  const int lane = tid & 63, wave = tid >> 6;
  const int wr = (wave >> 1) * 64, wc = (wave & 1) * 64;
  const int l16 = lane & 15, quad = lane >> 4;

  const int ar = tid >> 1, ahalf = tid & 1;
  const int apos = m0 + ar;
  const int a_t2s = lst[apos < cnt ? apos : cnt - 1];
  const unsigned short* aptr = act + (size_t)a_t2s * I_ + ahalf * 16;

  const int nq = tid & 31, kb = tid >> 5;
  const int bn = nq * 4, bk = kb * 4;

  f32x4 acc[4][4];
  const f32x4 fz = {0.f, 0.f, 0.f, 0.f};
#pragma unroll
  for (int mi = 0; mi < 4; ++mi)
#pragma unroll
    for (int ni = 0; ni < 4; ++ni) acc[mi][ni] = fz;

  for (int k0 = 0; k0 < I_; k0 += BK) {
    __syncthreads();
    {
      const uint4 A0 = *(const uint4*)(aptr + k0);
      const uint4 A1 = *(const uint4*)(aptr + k0 + 8);
      *(uint4*)&As[swz(ar, ahalf * 16)] = A0;
      *(uint4*)&As[swz(ar, ahalf * 16 + 8)] = A1;
    }
    stage_b(w2e + (size_t)(k0 + bk) * H_ + n0 + bn, Bs, bn, bk, H_);
    __syncthreads();

    bf16x8 af[4], bf[4];
#pragma unroll
    for (int mi = 0; mi < 4; ++mi)
      af[mi] = *(const bf16x8*)&As[swz(wr + mi * 16 + l16, quad * 8)];
#pragma unroll
    for (int ni = 0; ni < 4; ++ni)
      bf[ni] = *(const bf16x8*)&Bs[swz(wc + ni * 16 + l16, quad * 8)];
#pragma unroll
    for (int mi = 0; mi < 4; ++mi)
#pragma unroll
      for (int ni = 0; ni < 4; ++ni)
        acc[mi][ni] = __builtin_amdgcn_mfma_f32_16x16x32_bf16(af[mi], bf[ni], acc[mi][ni], 0, 0, 0);
  }

#pragma unroll
  for (int mi = 0; mi < 4; ++mi) {
    const int rbase = m0 + wr + mi * 16 + quad * 4;
#pragma unroll
    for (int r = 0; r < 4; ++r) {
      const int pos = rbase + r;
      if (pos < cnt) {
        const int t2s = lst[pos];
        const float wt = lw[pos];
        float* op = out + (size_t)(t2s >> 1) * H_ + n0 + wc + l16;
#pragma unroll
        for (int ni = 0; ni < 4; ++ni)
          atomicAdd(op + ni * 16, wt * acc[mi][ni][r]);
      }
    }
  }
}

extern "C" void kernel_launch(void* const* d_in, const int* in_sizes, int n_in,
                              void* d_out, int out_size, void* d_ws, size_t ws_size,
                              hipStream_t stream) {
  const float* x  = (const float*)d_in[0];
  const float* gw = (const float*)d_in[1];
  const float* w1 = (const float*)d_in[2];
  const float* w3 = (const float*)d_in[3];
  const float* w2 = (const float*)d_in[4];
  float* out = (float*)d_out;
  const int T = in_sizes[0] / H_;  // 8192

  // workspace layout (ws re-poisoned every call -> re-init/convert each call)
  char* ws = (char*)d_ws;
  int* counts = (int*)ws;                                        // 256 B
  int* list2s = (int*)(ws + 256);                                // E*T*4
  float* listw = (float*)(ws + 256 + (size_t)E_ * T * 4);        // E*T*4
  const size_t o_act = 256 + 2 * (size_t)E_ * T * 4;
  unsigned short* act = (unsigned short*)(ws + o_act);           // 2T*I*2
  const size_t o_xb  = o_act + 2 * (size_t)T * I_ * 2;
  const size_t whi   = (size_t)E_ * H_ * I_ * 2;                 // one bf16 weight set
  const size_t o_w1b = o_xb + (size_t)T * H_ * 2;
  const size_t o_w3b = o_w1b + whi;
  const size_t o_w2b = o_w3b + whi;
  const size_t need  = o_w2b + whi;                              // ~358 MB

  hipMemsetAsync(counts, 0, 256, stream);
  hipMemsetAsync(out, 0, (size_t)out_size * sizeof(float), stream);
  moe_router<<<T / 4, 64, 0, stream>>>(x, gw, counts, list2s, listw, T);

  if (ws_size >= need) {
    unsigned short* xb  = (unsigned short*)(ws + o_xb);
    unsigned short* w1b = (unsigned short*)(ws + o_w1b);
    unsigned short* w3b = (unsigned short*)(ws + o_w3b);
    unsigned short* w2b = (unsigned short*)(ws + o_w2b);
    convert_x<<<(size_t)T * H_ / 2048, 256, 0, stream>>>(x, xb);
    convert_wT<<<dim3(I_ / 128, H_ / 128, E_), 256, 0, stream>>>(w1, w1b, H_, I_);
    convert_wT<<<dim3(I_ / 128, H_ / 128, E_), 256, 0, stream>>>(w3, w3b, H_, I_);
    convert_wT<<<dim3(H_ / 128, I_ / 128, E_), 256, 0, stream>>>(w2, w2b, I_, H_);
    moe_gemm1_b16<<<dim3(I_ / BN, T / BM, E_), 256, 0, stream>>>(xb, w1b, w3b, counts, list2s, act, T);
    moe_gemm2_b16<<<dim3(H_ / BN, T / BM, E_), 256, 0, stream>>>(act, w2b, counts, list2s, listw, out, T);
  } else {
    moe_gemm1_f32<<<dim3(I_ / BN, T / BM, E_), 256, 0, stream>>>(x, w1, w3, counts, list2s, act, T);
    moe_gemm2_f32<<<dim3(H_ / BN, T / BM, E_), 256, 0, stream>>>(act, w2, counts, list2s, listw, out, T);
  }
}